// Round 6
// baseline (34.034 us; speedup 1.0000x reference)
//
#include <hip/hip_runtime.h>
#include <math.h>

#define HS 64
#define WS 208
#define HF 128
#define WF 416
#define NS (HS * WS)   // 13312
#define KH 20
#define KS 41
#define KK (KS * KS)   // 1681
#define NJ 27          // ceil(1681/64); last iter has 17 live lanes

// align_corners grid: f32 coords exactly as _resize_ac (arange(f32) * (f32(in-1)/f32(out-1))).
__device__ __forceinline__ void ac_idx(int o, int inN, float sc, int& i0, int& i1, float& w) {
#pragma clang fp contract(off)
    float s = (float)o * sc;
    float f = floorf(s);
    i0 = (int)f;
    i1 = min(i0 + 1, inN - 1);
    w = s - f;
}

// k_down: bit-faithful f32 resize of R -> ray4 (padded float4 triples) and of X ->
// normalized dir4; thread 0 also computes the f32 temperature.
__global__ void k_down(const float* __restrict__ R, const float* __restrict__ X,
                       const int* __restrict__ prog,
                       float4* __restrict__ ray4, float4* __restrict__ dir4,
                       float* __restrict__ tbuf) {
#pragma clang fp contract(off)
    int n = blockIdx.x * blockDim.x + threadIdx.x;
    if (n >= NS) return;
    if (n == 0) {
        double T64 = fmax(1e-8, 1e-4 / exp(0.1 * (double)prog[0]));
        tbuf[0] = (float)T64;   // same bits as np.float32(max(1e-8, 1e-4/exp(...)))
    }
    int y = n / WS, x = n - y * WS;
    int y0, y1, x0, x1; float wy, wx;
    ac_idx(y, HF, 127.0f / 63.0f, y0, y1, wy);
    ac_idx(x, WF, 415.0f / 207.0f, x0, x1, wx);
    float omwy = 1.0f - wy, omwx = 1.0f - wx;
    float r[3], d[3];
#pragma unroll
    for (int c = 0; c < 3; ++c) {
        const float* p = R + c * (HF * WF);
        float v00 = p[y0 * WF + x0], v10 = p[y1 * WF + x0];
        float v01 = p[y0 * WF + x1], v11 = p[y1 * WF + x1];
        float a0 = v00 * omwy; float b0 = v10 * wy; float t0 = a0 + b0;
        float a1 = v01 * omwy; float b1 = v11 * wy; float t1 = a1 + b1;
        float c0 = t0 * omwx; float c1 = t1 * wx;
        r[c] = c0 + c1;
        const float* q = X + c * (HF * WF);
        float u00 = q[y0 * WF + x0], u10 = q[y1 * WF + x0];
        float u01 = q[y0 * WF + x1], u11 = q[y1 * WF + x1];
        float e0 = u00 * omwy; float f0 = u10 * wy; float s0 = e0 + f0;
        float e1 = u01 * omwy; float f1 = u11 * wy; float s1 = e1 + f1;
        float g0 = s0 * omwx; float g1 = s1 * wx;
        d[c] = g0 + g1;
    }
    float q0 = d[0] * d[0]; float q1 = d[1] * d[1]; float q2 = d[2] * d[2];
    float ssq = (q0 + q1) + q2;
    float nrm = (float)sqrt((double)ssq);   // correctly-rounded f32 sqrt
    ray4[n] = make_float4(r[0], r[1], r[2], 0.0f);
    dir4[n] = make_float4(d[0] / nrm, d[1] / nrm, d[2] / nrm, 0.0f);
}

// One wave per HORIZONTAL PIXEL PAIR (wid, wid+1): same row -> shared srow and shared
// per-iter column bookkeeping; scol differs by delta in {0,1} so load_b = ray4[off+delta].
// Two independent logit/fmax chains double ILP. Pass 2: ballot-skip underflow-dead iters.
__global__ __launch_bounds__(256) void k_main(const float4* __restrict__ ray4,
                                              const float4* __restrict__ dir4,
                                              const float* __restrict__ tbuf,
                                              float* __restrict__ xn, float* __restrict__ yn) {
#pragma clang fp contract(off)
    int wave = (int)((blockIdx.x * blockDim.x + threadIdx.x) >> 6);
    int lane = (int)(threadIdx.x & 63);
    int wa = wave * 2;
    if (wa >= NS) return;
    int h = wa / WS, w = wa - h * WS;          // w even, w+1 in same row (WS even)
    int srow = min(max(h - KH, 0), HS - 1 - 2 * KH);
    int sca  = min(max(w - KH, 0), WS - 1 - 2 * KH);
    int scb  = min(max(w + 1 - KH, 0), WS - 1 - 2 * KH);
    int delta = scb - sca;                     // 0 or 1

    float4 da4 = dir4[wa];
    float4 db4 = dir4[wa + 1];
    float a0c = da4.x, a1c = da4.y, a2c = da4.z;
    float b0c = db4.x, b1c = db4.y, b2c = db4.z;
    float Tf = tbuf[0];

    // per-lane start in the 41x41 window: k = lane -> (k1,k2); advance k += 64 per iter.
    int k1i = (lane >= KS) ? 1 : 0;
    int k2i = lane - k1i * KS;
    int off = (srow + k1i) * WS + sca + k2i;
    int colk = k2i;                            // running k2 in [0,40]

    float lga[NJ], lgb[NJ];
    float ma = -INFINITY, mb = -INFINITY;
#pragma unroll
    for (int j = 0; j < NJ - 1; ++j) {
        float4 va = ray4[off];
        float4 vb = ray4[off + delta];
        float pa0 = a0c * va.x; float pa1 = a1c * va.y; float pa2 = a2c * va.z;
        float la = (pa0 + pa1) + pa2;
        float pb0 = b0c * vb.x; float pb1 = b1c * vb.y; float pb2 = b2c * vb.z;
        float lb = (pb0 + pb1) + pb2;
        lga[j] = la; lgb[j] = lb;
        ma = fmaxf(ma, la); mb = fmaxf(mb, lb);
        int cn = colk + 23;                    // k += 64 = 1*41 + 23
        bool cr = cn >= KS;
        colk = cr ? cn - KS : cn;
        off += cr ? (2 * WS - 18) : (WS + 23);
    }
    {   // last iteration: k = lane + 1664, live iff lane < 17
        float la = -INFINITY, lb = -INFINITY;
        if (lane < KK - 64 * (NJ - 1)) {
            float4 va = ray4[off];
            float4 vb = ray4[off + delta];
            float pa0 = a0c * va.x; float pa1 = a1c * va.y; float pa2 = a2c * va.z;
            la = (pa0 + pa1) + pa2;
            float pb0 = b0c * vb.x; float pb1 = b1c * vb.y; float pb2 = b2c * vb.z;
            lb = (pb0 + pb1) + pb2;
        }
        lga[NJ - 1] = la; lgb[NJ - 1] = lb;
        ma = fmaxf(ma, la); mb = fmaxf(mb, lb);
    }
#pragma unroll
    for (int s = 1; s < 64; s <<= 1) {
        ma = fmaxf(ma, __shfl_xor(ma, s));
        mb = fmaxf(mb, __shfl_xor(mb, s));
    }

    float zma = ma / Tf, zmb = mb / Tf;        // monotone div: == ref's max-of-(l/T)
    float tha = ma - 0.004f, thb = mb - 0.004f; // below: z-zm < -108 -> f32 weight == 0

    float sea = 0.f, sra = 0.f, sca_ = 0.f;
    float seb = 0.f, srb = 0.f, scb_ = 0.f;
#pragma unroll
    for (int j = 0; j < NJ; ++j) {
        bool la = lga[j] > tha, lb = lgb[j] > thb;
        if (__ballot(la || lb)) {
            int k = lane + 64 * j;
            int kk1 = k / KS;
            int kk2 = k - kk1 * KS;
            float fr = (float)(srow + kk1);
            if (__ballot(la)) {
                float z = lga[j] / Tf;                 // bit-identical to ref's logits/T
                float arg = (z - zma) * 1.442695040888963f;
                float e = la ? __builtin_amdgcn_exp2f(arg) : 0.0f;
                sea += e; sra += e * fr; sca_ += e * (float)(sca + kk2);
            }
            if (__ballot(lb)) {
                float z = lgb[j] / Tf;
                float arg = (z - zmb) * 1.442695040888963f;
                float e = lb ? __builtin_amdgcn_exp2f(arg) : 0.0f;
                seb += e; srb += e * fr; scb_ += e * (float)(scb + kk2);
            }
        }
    }
#pragma unroll
    for (int s = 1; s < 64; s <<= 1) {
        sea += __shfl_xor(sea, s); sra += __shfl_xor(sra, s); sca_ += __shfl_xor(sca_, s);
        seb += __shfl_xor(seb, s); srb += __shfl_xor(srb, s); scb_ += __shfl_xor(scb_, s);
    }
    if (lane == 0) {
        double ixa = (double)sra / (double)sea, iya = (double)sca_ / (double)sea;
        xn[wa] = (float)(2.0 * ixa / (double)(HS - 1) - 1.0);
        yn[wa] = (float)(2.0 * iya / (double)(WS - 1) - 1.0);
        double ixb = (double)srb / (double)seb, iyb = (double)scb_ / (double)seb;
        xn[wa + 1] = (float)(2.0 * ixb / (double)(HS - 1) - 1.0);
        yn[wa + 1] = (float)(2.0 * iyb / (double)(WS - 1) - 1.0);
    }
}

// Bilinear upsample (align_corners) of (Yn, Xn) to full res, interleaved channels.
__global__ void k_up(const float* __restrict__ xn, const float* __restrict__ yn,
                     float* __restrict__ out) {
#pragma clang fp contract(off)
    int i = blockIdx.x * blockDim.x + threadIdx.x;
    if (i >= HF * WF) return;
    int hh = i / WF, ww = i - hh * WF;
    int y0, y1, x0, x1; float wy, wx;
    ac_idx(hh, HS, 63.0f / 127.0f, y0, y1, wy);
    ac_idx(ww, WS, 207.0f / 415.0f, x0, x1, wx);
    float omwy = 1.0f - wy, omwx = 1.0f - wx;
    float a0, b0, t0, t1;
    a0 = xn[y0 * WS + x0] * omwy; b0 = xn[y1 * WS + x0] * wy; t0 = a0 + b0;
    a0 = xn[y0 * WS + x1] * omwy; b0 = xn[y1 * WS + x1] * wy; t1 = a0 + b0;
    float bx = t0 * omwx + t1 * wx;     // Xn upsampled
    a0 = yn[y0 * WS + x0] * omwy; b0 = yn[y1 * WS + x0] * wy; t0 = a0 + b0;
    a0 = yn[y0 * WS + x1] * omwy; b0 = yn[y1 * WS + x1] * wy; t1 = a0 + b0;
    float ay = t0 * omwx + t1 * wx;     // Yn upsampled
    out[2 * i]     = ay;
    out[2 * i + 1] = bx;
}

extern "C" void kernel_launch(void* const* d_in, const int* in_sizes, int n_in,
                              void* d_out, int out_size, void* d_ws, size_t ws_size,
                              hipStream_t stream) {
    const float* R = (const float*)d_in[0];
    const float* X = (const float*)d_in[1];
    const int* prog = (const int*)d_in[2];
    float4* ray4 = (float4*)d_ws;            // NS float4
    float4* dir4 = ray4 + NS;                // NS float4
    float* xn   = (float*)(dir4 + NS);       // NS
    float* yn   = xn + NS;                   // NS
    float* tbuf = yn + NS;                   // 1
    float* out  = (float*)d_out;

    k_down<<<(NS + 255) / 256, 256, 0, stream>>>(R, X, prog, ray4, dir4, tbuf);
    // one wave per pixel pair: NS/2 waves = NS*32 threads
    k_main<<<(NS * 32 + 255) / 256, 256, 0, stream>>>(ray4, dir4, tbuf, xn, yn);
    k_up<<<(HF * WF + 255) / 256, 256, 0, stream>>>(xn, yn, out);
}

// Round 7
// 30.789 us; speedup vs baseline: 1.1054x; 1.1054x over previous
//
#include <hip/hip_runtime.h>
#include <math.h>

#define HS 64
#define WS 208
#define HF 128
#define WF 416
#define NS (HS * WS)   // 13312
#define KH 20
#define KS 41
#define KK (KS * KS)   // 1681
#define NJ2 7          // ceil(1681/256); last iter: tid<145 live

// align_corners grid: f32 coords exactly as _resize_ac (arange(f32) * (f32(in-1)/f32(out-1))).
__device__ __forceinline__ void ac_idx(int o, int inN, float sc, int& i0, int& i1, float& w) {
#pragma clang fp contract(off)
    float s = (float)o * sc;
    float f = floorf(s);
    i0 = (int)f;
    i1 = min(i0 + 1, inN - 1);
    w = s - f;
}

// k_down: bit-faithful f32 resize of R -> ray4 (padded float4 triples) and of X ->
// normalized dir4; thread 0 also computes the f32 temperature.
__global__ void k_down(const float* __restrict__ R, const float* __restrict__ X,
                       const int* __restrict__ prog,
                       float4* __restrict__ ray4, float4* __restrict__ dir4,
                       float* __restrict__ tbuf) {
#pragma clang fp contract(off)
    int n = blockIdx.x * blockDim.x + threadIdx.x;
    if (n >= NS) return;
    if (n == 0) {
        double T64 = fmax(1e-8, 1e-4 / exp(0.1 * (double)prog[0]));
        tbuf[0] = (float)T64;   // same bits as np.float32(max(1e-8, 1e-4/exp(...)))
    }
    int y = n / WS, x = n - y * WS;
    int y0, y1, x0, x1; float wy, wx;
    ac_idx(y, HF, 127.0f / 63.0f, y0, y1, wy);
    ac_idx(x, WF, 415.0f / 207.0f, x0, x1, wx);
    float omwy = 1.0f - wy, omwx = 1.0f - wx;
    float r[3], d[3];
#pragma unroll
    for (int c = 0; c < 3; ++c) {
        const float* p = R + c * (HF * WF);
        float v00 = p[y0 * WF + x0], v10 = p[y1 * WF + x0];
        float v01 = p[y0 * WF + x1], v11 = p[y1 * WF + x1];
        float a0 = v00 * omwy; float b0 = v10 * wy; float t0 = a0 + b0;
        float a1 = v01 * omwy; float b1 = v11 * wy; float t1 = a1 + b1;
        float c0 = t0 * omwx; float c1 = t1 * wx;
        r[c] = c0 + c1;
        const float* q = X + c * (HF * WF);
        float u00 = q[y0 * WF + x0], u10 = q[y1 * WF + x0];
        float u01 = q[y0 * WF + x1], u11 = q[y1 * WF + x1];
        float e0 = u00 * omwy; float f0 = u10 * wy; float s0 = e0 + f0;
        float e1 = u01 * omwy; float f1 = u11 * wy; float s1 = e1 + f1;
        float g0 = s0 * omwx; float g1 = s1 * wx;
        d[c] = g0 + g1;
    }
    float q0 = d[0] * d[0]; float q1 = d[1] * d[1]; float q2 = d[2] * d[2];
    float ssq = (q0 + q1) + q2;
    float nrm = (float)sqrt((double)ssq);   // correctly-rounded f32 sqrt
    ray4[n] = make_float4(r[0], r[1], r[2], 0.0f);
    dir4[n] = make_float4(d[0] / nrm, d[1] / nrm, d[2] / nrm, 0.0f);
}

// One BLOCK (256 threads, 4 waves) per pixel: 1681 window elements split across the
// block (7 iters/thread). Wave shfl-reduce + tiny LDS cross-wave reduce. Pass 2
// ballot-skips underflow-dead iterations (weight exactly 0 in f32, as in ref).
__global__ __launch_bounds__(256) void k_main(const float4* __restrict__ ray4,
                                              const float4* __restrict__ dir4,
                                              const float* __restrict__ tbuf,
                                              float* __restrict__ xn, float* __restrict__ yn) {
#pragma clang fp contract(off)
    int pix = blockIdx.x;
    int tid = (int)threadIdx.x;
    int lane = tid & 63;
    int wid = tid >> 6;
    int h = pix / WS, w = pix - h * WS;
    int srow = min(max(h - KH, 0), HS - 1 - 2 * KH);
    int scol = min(max(w - KH, 0), WS - 1 - 2 * KH);

    float4 dv = dir4[pix];
    float d0 = dv.x, d1 = dv.y, d2 = dv.z;
    float Tf = tbuf[0];

    // k = tid -> (k1,k2); exact floor(tid/41) for tid<256 via (tid*25)>>10.
    int k1i = (tid * 25) >> 10;
    int k2i = tid - k1i * KS;
    int off = (srow + k1i) * WS + scol + k2i;
    int colk = k2i;

    // Pass 1: raw logits, bit-exact ((p0+p1)+p2), running max. k += 256 = 6*41+10.
    float lg[NJ2];
    float m = -INFINITY;
#pragma unroll
    for (int j = 0; j < NJ2 - 1; ++j) {
        float4 v = ray4[off];
        float p0 = d0 * v.x; float p1 = d1 * v.y; float p2 = d2 * v.z;
        float l = (p0 + p1) + p2;
        lg[j] = l;
        m = fmaxf(m, l);
        int cn = colk + 10;
        bool cr = cn >= KS;
        colk = cr ? cn - KS : cn;
        off += cr ? (7 * WS - 31) : (6 * WS + 10);
    }
    {   // j=6: k = tid + 1536, live iff tid < 145
        float l = -INFINITY;
        if (tid < KK - 256 * (NJ2 - 1)) {
            float4 v = ray4[off];
            float p0 = d0 * v.x; float p1 = d1 * v.y; float p2 = d2 * v.z;
            l = (p0 + p1) + p2;
        }
        lg[NJ2 - 1] = l;
        m = fmaxf(m, l);
    }
#pragma unroll
    for (int s = 1; s < 64; s <<= 1) m = fmaxf(m, __shfl_xor(m, s));

    __shared__ float smax[4];
    __shared__ float ssum[4][3];
    if (lane == 0) smax[wid] = m;
    __syncthreads();
    m = fmaxf(fmaxf(smax[0], smax[1]), fmaxf(smax[2], smax[3]));

    float zm = m / Tf;                 // monotone div: == ref's max-of-(l/T)
    float thresh = m - 0.004f;         // below: z-zm < -108 -> f32 weight exactly 0

    // Pass 2: incremental (k1,k2) replay; only live-ballot iterations pay div+exp.
    float se = 0.f, sr = 0.f, sc = 0.f;
    int c1 = k1i, c2 = k2i;
#pragma unroll
    for (int j = 0; j < NJ2; ++j) {
        bool a = lg[j] > thresh;       // dead lanes hold -INF -> false
        if (__ballot(a)) {
            float z = lg[j] / Tf;      // bit-identical to ref's logits/T
            float arg = (z - zm) * 1.442695040888963f;
            float e = a ? __builtin_amdgcn_exp2f(arg) : 0.0f;
            se += e;
            sr += e * (float)(srow + c1);
            sc += e * (float)(scol + c2);
        }
        int cn = c2 + 10;
        bool cr = cn >= KS;
        c2 = cr ? cn - KS : cn;
        c1 += cr ? 7 : 6;
    }
#pragma unroll
    for (int s = 1; s < 64; s <<= 1) {
        se += __shfl_xor(se, s);
        sr += __shfl_xor(sr, s);
        sc += __shfl_xor(sc, s);
    }
    if (lane == 0) { ssum[wid][0] = se; ssum[wid][1] = sr; ssum[wid][2] = sc; }
    __syncthreads();
    if (tid == 0) {
        float SE = (ssum[0][0] + ssum[1][0]) + (ssum[2][0] + ssum[3][0]);
        float SR = (ssum[0][1] + ssum[1][1]) + (ssum[2][1] + ssum[3][1]);
        float SC = (ssum[0][2] + ssum[1][2]) + (ssum[2][2] + ssum[3][2]);
        double ix = (double)SR / (double)SE, iy = (double)SC / (double)SE;
        xn[pix] = (float)(2.0 * ix / (double)(HS - 1) - 1.0);
        yn[pix] = (float)(2.0 * iy / (double)(WS - 1) - 1.0);
    }
}

// Bilinear upsample (align_corners) of (Yn, Xn) to full res, interleaved channels.
__global__ void k_up(const float* __restrict__ xn, const float* __restrict__ yn,
                     float* __restrict__ out) {
#pragma clang fp contract(off)
    int i = blockIdx.x * blockDim.x + threadIdx.x;
    if (i >= HF * WF) return;
    int hh = i / WF, ww = i - hh * WF;
    int y0, y1, x0, x1; float wy, wx;
    ac_idx(hh, HS, 63.0f / 127.0f, y0, y1, wy);
    ac_idx(ww, WS, 207.0f / 415.0f, x0, x1, wx);
    float omwy = 1.0f - wy, omwx = 1.0f - wx;
    float a0, b0, t0, t1;
    a0 = xn[y0 * WS + x0] * omwy; b0 = xn[y1 * WS + x0] * wy; t0 = a0 + b0;
    a0 = xn[y0 * WS + x1] * omwy; b0 = xn[y1 * WS + x1] * wy; t1 = a0 + b0;
    float bx = t0 * omwx + t1 * wx;     // Xn upsampled
    a0 = yn[y0 * WS + x0] * omwy; b0 = yn[y1 * WS + x0] * wy; t0 = a0 + b0;
    a0 = yn[y0 * WS + x1] * omwy; b0 = yn[y1 * WS + x1] * wy; t1 = a0 + b0;
    float ay = t0 * omwx + t1 * wx;     // Yn upsampled
    out[2 * i]     = ay;
    out[2 * i + 1] = bx;
}

extern "C" void kernel_launch(void* const* d_in, const int* in_sizes, int n_in,
                              void* d_out, int out_size, void* d_ws, size_t ws_size,
                              hipStream_t stream) {
    const float* R = (const float*)d_in[0];
    const float* X = (const float*)d_in[1];
    const int* prog = (const int*)d_in[2];
    float4* ray4 = (float4*)d_ws;            // NS float4
    float4* dir4 = ray4 + NS;                // NS float4
    float* xn   = (float*)(dir4 + NS);       // NS
    float* yn   = xn + NS;                   // NS
    float* tbuf = yn + NS;                   // 1
    float* out  = (float*)d_out;

    k_down<<<(NS + 255) / 256, 256, 0, stream>>>(R, X, prog, ray4, dir4, tbuf);
    k_main<<<NS, 256, 0, stream>>>(ray4, dir4, tbuf, xn, yn);   // one block per pixel
    k_up<<<(HF * WF + 255) / 256, 256, 0, stream>>>(xn, yn, out);
}